// Round 18
// baseline (1938.672 us; speedup 1.0000x reference)
//
#include <hip/hip_runtime.h>
#include <hip/hip_bf16.h>

#define NN 100000
#define NE 300000
#define NG 4096
#define EMB 256
#define NLAYERS 5

typedef unsigned short u16;
typedef unsigned int u32;

typedef short bf16x8 __attribute__((ext_vector_type(8)));
typedef float f32x4 __attribute__((ext_vector_type(4)));

__device__ __forceinline__ float b2f(u16 u){
    union { float f; u32 i; } v; v.i = ((u32)u) << 16; return v.f;
}
__device__ __forceinline__ u16 f2b(float f){
    __hip_bfloat16 h = __float2bfloat16(f);   // RNE
    union { __hip_bfloat16 h; u16 u; } v; v.h = h; return v.u;
}
// inline BN finalize: sc/sh for feature f from raw sums
__device__ __forceinline__ void bnsc_f(const float* __restrict__ stats,
        const float* __restrict__ gamma, const float* __restrict__ beta,
        int f, float& sc, float& sh)
{
    const float inv = 1.0f / (float)NN;
    float mean = stats[f] * inv;
    float var  = stats[256+f] * inv - mean*mean;
    float is = rsqrtf(var + 1e-5f);
    sc = gamma[f] * is;
    sh = fmaf(-mean, sc, beta[f]);
}

// ---------------- x embedding: t = x @ xW.T + xb  (bf16 out, raw/pre-BN) ------
#define XNB 32
__global__ __launch_bounds__(256) void embed_x(const float* __restrict__ x,
        const float* __restrict__ W, const float* __restrict__ b,
        u16* __restrict__ t)
{
    __shared__ float sW[256][41];
    __shared__ float sx[XNB][40];
    int tid = threadIdx.x;
    for (int i = tid; i < 256*40; i += 256) sW[i/40][i%40] = W[i];
    int n0 = blockIdx.x * XNB;      // 100000 = 3125*32 exact
    for (int i = tid; i < XNB*40; i += 256) {
        int j = i/40, k = i%40;
        sx[j][k] = x[(size_t)(n0+j)*40 + k];
    }
    __syncthreads();
    float bb = b[tid];
    for (int j = 0; j < XNB; ++j) {
        float a = bb;
        #pragma unroll
        for (int k = 0; k < 40; ++k) a = fmaf(sW[tid][k], sx[j][k], a);
        t[(size_t)(n0+j)*EMB + tid] = f2b(a);
    }
}

// ---------------- W -> bf16 ----------------
__global__ void wconv(const float* __restrict__ W, u16* __restrict__ Wb, int n)
{
    int i = blockIdx.x*256 + threadIdx.x;
    if (i < n) Wb[i] = f2b(W[i]);
}

// ---------------- eW transpose: eWt[k*256+f] = eW[f*10+k] ----------------
__global__ void ewt_kernel(const float* __restrict__ eW, float* __restrict__ eWt)
{
    int i = blockIdx.x*256 + threadIdx.x;
    if (i < 2560) { int f = i/10, k = i%10; eWt[k*256 + f] = eW[i]; }
}

// ---------------- histograms ----------------
__global__ void hist_kernel(const int* __restrict__ row, const int* __restrict__ col,
        int* __restrict__ rcnt, int* __restrict__ ccnt, int E)
{
    int e = blockIdx.x*256 + threadIdx.x;
    if (e < E) {
        atomicAdd(&rcnt[row[e]], 1);
        atomicAdd(&ccnt[col[e]], 1);
    }
}

__global__ void deg_fin(const int* __restrict__ rcnt, float* __restrict__ dinv,
                        float* __restrict__ invdg, int N)
{
    int n = blockIdx.x*256 + threadIdx.x;
    if (n < N) {
        float d = (float)rcnt[n] + 1.0f;
        dinv[n]  = rsqrtf(d);
        invdg[n] = 1.0f/d;
    }
}

// ---------------- prefix scan (3 kernels) ----------------
__global__ void scan1(const int* __restrict__ cnt, int* __restrict__ bsum, int N)
{
    __shared__ int sh[256];
    int t = threadIdx.x, i = blockIdx.x*256 + t;
    sh[t] = (i < N) ? cnt[i] : 0;
    __syncthreads();
    for (int off = 128; off > 0; off >>= 1) {
        if (t < off) sh[t] += sh[t+off];
        __syncthreads();
    }
    if (t == 0) bsum[blockIdx.x] = sh[0];
}

__global__ __launch_bounds__(512) void scan2(const int* __restrict__ bsum,
        int* __restrict__ bbase, int* __restrict__ coff, int nb)
{
    __shared__ int a[512], b[512];
    int t = threadIdx.x;
    a[t] = (t < nb) ? bsum[t] : 0;
    __syncthreads();
    int* src = a; int* dst = b;
    for (int off = 1; off < 512; off <<= 1) {
        dst[t] = (t >= off) ? src[t-off] + src[t] : src[t];
        __syncthreads();
        int* tmp = src; src = dst; dst = tmp;
    }
    bbase[t] = t ? src[t-1] : 0;
    if (t == 0) coff[NN] = NE;
}

__global__ void scan3(const int* __restrict__ cnt, const int* __restrict__ bbase,
        int* __restrict__ coff, int N)
{
    __shared__ int a[256], b[256];
    int t = threadIdx.x, i = blockIdx.x*256 + t;
    a[t] = (i < N) ? cnt[i] : 0;
    __syncthreads();
    int* src = a; int* dst = b;
    for (int off = 1; off < 256; off <<= 1) {
        dst[t] = (t >= off) ? src[t-off] + src[t] : src[t];
        __syncthreads();
        int* tmp = src; src = dst; dst = tmp;
    }
    if (i < N) coff[i] = bbase[blockIdx.x] + (t ? src[t-1] : 0);
}

// CSR fill: epack[p]={row, norm-bits}; eab[p][16] = bf16 eattr (10 used)
__global__ void csr_fill(const int* __restrict__ row, const int* __restrict__ col,
        const float* __restrict__ eattr, const int* __restrict__ coff,
        const float* __restrict__ dinv, int* __restrict__ fill,
        int2* __restrict__ epack, u16* __restrict__ eab, int E)
{
    int e = blockIdx.x*256 + threadIdx.x;
    if (e < E) {
        int c = col[e], r = row[e];
        int p = coff[c] + atomicAdd(&fill[c], 1);
        int2 ep; ep.x = r; ep.y = __float_as_int(dinv[r] * dinv[c]);
        epack[p] = ep;
        #pragma unroll
        for (int k = 0; k < 10; ++k) eab[(size_t)p*16 + k] = f2b(eattr[(size_t)e*10 + k]);
        #pragma unroll
        for (int k = 10; k < 16; ++k) eab[(size_t)p*16 + k] = 0;
    }
}

// ---------------- MFMA GEMM v6b: BM=64, 4 waves, 2-pass epilogue, 8 blk/CU ----
// C[m][o] = sum_k affine(A[m][k]) * Wb[o][k] + bias[o]
#define CS3 136   // epilogue row stride (u16): 68 words == 4 mod 32 banks
__global__ __launch_bounds__(256, 8) void gemm_mfma(const u16* __restrict__ A,
        const u16* __restrict__ Wb, const float* __restrict__ bias,
        const float* __restrict__ stats, const float* __restrict__ gamma,
        const float* __restrict__ beta, int doBN,
        u16* __restrict__ C, int M)
{
    __shared__ __align__(16) char smem[18432];   // As0 8K | As1 8K | sc/sh 2K; Cs 17.4K overlays
    u16* As0 = (u16*)smem;
    u16* As1 = (u16*)(smem + 8192);
    float* scS = (float*)(smem + 16384);
    float* shS = scS + 256;
    const int tid = threadIdx.x;
    if (doBN) {
        float s, h; bnsc_f(stats, gamma, beta, tid, s, h);
        scS[tid] = s; shS[tid] = h;
    }
    const int lane = tid & 63;
    const int wn = tid >> 6;                 // 0..3: 64-col panel
    const int m0 = blockIdx.x * 64;
    const int r8 = tid >> 3;                 // 0..31
    const int ch = tid & 7;
    const int sw = ch ^ (r8 & 7);            // (r8+32)&7 == r8&7
    const int ga0 = min(m0 + r8,      M-1);
    const int ga1 = min(m0 + r8 + 32, M-1);
    const int c  = lane >> 4;
    const int rl = lane & 15;
    const int nb0 = wn*64 + rl;              // B row base for this lane

    uint4 ra0, ra1;
    #define LOADK(k0) do {                                                     \
        ra0 = *reinterpret_cast<const uint4*>(&A[(size_t)ga0*256 + (k0) + ch*8]); \
        ra1 = *reinterpret_cast<const uint4*>(&A[(size_t)ga1*256 + (k0) + ch*8]); \
    } while(0)

    #define STAGE(dst, k0v) do {                                               \
        uint4 va0 = ra0, va1 = ra1;                                            \
        if (doBN) {                                                            \
            int kk = (k0v) + ch*8;                                             \
            u32 w0[4] = {va0.x, va0.y, va0.z, va0.w};                          \
            u32 w1[4] = {va1.x, va1.y, va1.z, va1.w};                          \
            _Pragma("unroll")                                                  \
            for (int j = 0; j < 4; ++j) {                                      \
                float l0 = b2f((u16)(w0[j] & 0xffffu)), h0 = b2f((u16)(w0[j] >> 16)); \
                float l1 = b2f((u16)(w1[j] & 0xffffu)), h1 = b2f((u16)(w1[j] >> 16)); \
                float s0 = scS[kk+2*j], s1 = scS[kk+2*j+1];                    \
                float b0 = shS[kk+2*j], b1 = shS[kk+2*j+1];                    \
                l0 = fmaxf(fmaf(l0, s0, b0), 0.f); h0 = fmaxf(fmaf(h0, s1, b1), 0.f); \
                l1 = fmaxf(fmaf(l1, s0, b0), 0.f); h1 = fmaxf(fmaf(h1, s1, b1), 0.f); \
                w0[j] = (u32)f2b(l0) | ((u32)f2b(h0) << 16);                   \
                w1[j] = (u32)f2b(l1) | ((u32)f2b(h1) << 16);                   \
            }                                                                  \
            va0.x=w0[0]; va0.y=w0[1]; va0.z=w0[2]; va0.w=w0[3];                \
            va1.x=w1[0]; va1.y=w1[1]; va1.z=w1[2]; va1.w=w1[3];                \
        }                                                                      \
        *reinterpret_cast<uint4*>(&(dst)[((r8     )*8 + sw)*8]) = va0;         \
        *reinterpret_cast<uint4*>(&(dst)[((r8 + 32)*8 + sw)*8]) = va1;         \
    } while(0)

    f32x4 acc[4][4] = {};
    #define KSTEP(cur, k0v) do {                                               \
        _Pragma("unroll")                                                      \
        for (int kt = 0; kt < 2; ++kt) {                                       \
            bf16x8 af[4], bfr[4];                                              \
            _Pragma("unroll")                                                  \
            for (int f = 0; f < 4; ++f) {                                      \
                bfr[f] = *reinterpret_cast<const bf16x8*>(                     \
                    &Wb[(size_t)(nb0 + f*16)*256 + (k0v) + (kt*4 + c)*8]);     \
                int rA = f*16 + rl;                                            \
                int cha = (kt*4 + c) ^ (rA & 7);                               \
                af[f] = *reinterpret_cast<const bf16x8*>(&(cur)[(rA*8 + cha)*8]); \
            }                                                                  \
            _Pragma("unroll")                                                  \
            for (int fm = 0; fm < 4; ++fm)                                     \
                _Pragma("unroll")                                              \
                for (int fn = 0; fn < 4; ++fn)                                 \
                    acc[fm][fn] = __builtin_amdgcn_mfma_f32_16x16x32_bf16(     \
                        af[fm], bfr[fn], acc[fm][fn], 0, 0, 0);                \
        }                                                                      \
    } while(0)

    LOADK(0);
    if (doBN) __syncthreads();   // scS/shS visible before first affine
    STAGE(As0, 0);
    LOADK(64);
    __syncthreads();             // As0 visible
    STAGE(As1, 64); LOADK(128);
    KSTEP(As0, 0);
    __syncthreads();
    STAGE(As0, 128); LOADK(192);
    KSTEP(As1, 64);
    __syncthreads();
    STAGE(As1, 192);
    KSTEP(As0, 128);
    __syncthreads();
    KSTEP(As1, 192);
    __syncthreads();             // before Cs overlays As/scsh
    #undef LOADK
    #undef STAGE
    #undef KSTEP

    // ---- epilogue: 2-pass LDS bounce (128 cols each) -> coalesced stores ----
    u16* Cs = (u16*)smem;        // 64 x CS3 u16 = 17408 B
    const int cn = lane & 15, rq = lane >> 4;
    #pragma unroll
    for (int pp = 0; pp < 2; ++pp) {
        if ((wn >> 1) == pp) {               // waves {2pp, 2pp+1} own this half
            int cl0 = (wn & 1)*64;
            #pragma unroll
            for (int fn = 0; fn < 4; ++fn) {
                int n = wn*64 + fn*16 + cn;  // global col
                float bb = bias[n];
                int nl = cl0 + fn*16 + cn;   // local col within half
                #pragma unroll
                for (int fm = 0; fm < 4; ++fm) {
                    int rbase = fm*16 + rq*4;
                    #pragma unroll
                    for (int r = 0; r < 4; ++r)
                        Cs[(rbase + r)*CS3 + nl] = f2b(acc[fm][fn][r] + bb);
                }
            }
        }
        __syncthreads();
        #pragma unroll
        for (int it = 0; it < 4; ++it) {
            int idx = tid + it*256;          // 0..1023
            int rowi = idx >> 4;             // 0..63
            int c8  = (idx & 15) * 8;        // 0..120
            int m = m0 + rowi;
            if (m < M)
                *reinterpret_cast<uint4*>(&C[(size_t)m*256 + pp*128 + c8]) =
                    *reinterpret_cast<const uint4*>(&Cs[rowi*CS3 + c8]);
        }
        __syncthreads();
    }
}

// ================= gather+combine: on-the-fly edge MLP (round-12 best) ========
#define GFB 4
#define NGROUPS (NN/GFB)
__global__ __launch_bounds__(256) void gather_combine_w(const int2* __restrict__ epack,
        const u16* __restrict__ eab, const int* __restrict__ coff,
        const float* __restrict__ eWt, const float* __restrict__ ebv,
        const u16* __restrict__ hx, const float* __restrict__ rootv,
        const float* __restrict__ invdg, const float* __restrict__ statsPrev,
        const float* __restrict__ gammaPrev, const float* __restrict__ betaPrev,
        int doBN, u16* __restrict__ t, float* __restrict__ stats, int N)
{
    __shared__ float red[4][512];
    const int wid = threadIdx.x >> 6, lane = threadIdx.x & 63;
    const int f4 = lane*4;
    float w[4][10], bb[4];
    #pragma unroll
    for (int k = 0; k < 10; ++k) {
        float4 wv = *reinterpret_cast<const float4*>(&eWt[k*256 + f4]);
        w[0][k] = wv.x; w[1][k] = wv.y; w[2][k] = wv.z; w[3][k] = wv.w;
    }
    { float4 bv = *reinterpret_cast<const float4*>(&ebv[f4]);
      bb[0]=bv.x; bb[1]=bv.y; bb[2]=bv.z; bb[3]=bv.w; }
    float4 root = *reinterpret_cast<const float4*>(&rootv[f4]);
    float sc[4] = {1,1,1,1}, sh[4] = {0,0,0,0};
    if (doBN) {
        #pragma unroll
        for (int j = 0; j < 4; ++j)
            bnsc_f(statsPrev, gammaPrev, betaPrev, f4+j, sc[j], sh[j]);
    }
    float sacc[4] = {0,0,0,0}, s2acc[4] = {0,0,0,0};

    for (int g = blockIdx.x*4 + wid; g < NGROUPS; g += gridDim.x*4) {
        const int nb = g*GFB;
        int c1 = coff[nb+1], c2 = coff[nb+2], c3 = coff[nb+3], c4 = coff[nb+4];
        int s = coff[nb], e = c4;
        int jn = 0, cend = c1;
        float acc[4] = {0,0,0,0};

        #define FLUSH() do {                                                   \
            int n_ = nb + jn;                                                  \
            size_t idx_ = (size_t)n_*EMB + f4;                                 \
            uint2 hv_ = *reinterpret_cast<const uint2*>(&t[idx_]);             \
            uint2 xv_ = *reinterpret_cast<const uint2*>(&hx[idx_]);            \
            float id_ = invdg[n_];                                             \
            float hh_[4] = { b2f((u16)(hv_.x&0xffffu)), b2f((u16)(hv_.x>>16)), \
                             b2f((u16)(hv_.y&0xffffu)), b2f((u16)(hv_.y>>16)) };\
            float xx_[4] = { b2f((u16)(xv_.x&0xffffu)), b2f((u16)(xv_.x>>16)), \
                             b2f((u16)(xv_.y&0xffffu)), b2f((u16)(xv_.y>>16)) };\
            float rt_[4] = { root.x, root.y, root.z, root.w };                 \
            u16 ov_[4];                                                        \
            _Pragma("unroll")                                                  \
            for (int jj = 0; jj < 4; ++jj) {                                   \
                float hin_ = hh_[jj];                                          \
                if (doBN) hin_ = fmaxf(fmaf(hin_, sc[jj], sh[jj]), 0.f);       \
                float rv_ = xx_[jj] + rt_[jj];                                 \
                rv_ = rv_ > 0.f ? rv_ : 0.f;                                   \
                float tv_ = hin_ + acc[jj] + rv_*id_;                          \
                ov_[jj] = f2b(tv_);                                            \
                sacc[jj] += tv_; s2acc[jj] += tv_*tv_;                         \
                acc[jj] = 0.f;                                                 \
            }                                                                  \
            uint2 o_; o_.x = (u32)ov_[0] | ((u32)ov_[1]<<16);                  \
            o_.y = (u32)ov_[2] | ((u32)ov_[3]<<16);                            \
            *reinterpret_cast<uint2*>(&t[idx_]) = o_;                          \
            ++jn; cend = (jn==1) ? c2 : (jn==2) ? c3 : c4;                     \
        } while(0)

        #define CONSUME(nm, hvv, alo, ahi) do {                                \
            float hf_[4] = { b2f((u16)((hvv).x&0xffffu)), b2f((u16)((hvv).x>>16)),\
                             b2f((u16)((hvv).y&0xffffu)), b2f((u16)((hvv).y>>16)) };\
            float at_[10];                                                     \
            at_[0]=b2f((u16)((alo).x&0xffffu)); at_[1]=b2f((u16)((alo).x>>16));\
            at_[2]=b2f((u16)((alo).y&0xffffu)); at_[3]=b2f((u16)((alo).y>>16));\
            at_[4]=b2f((u16)((alo).z&0xffffu)); at_[5]=b2f((u16)((alo).z>>16));\
            at_[6]=b2f((u16)((alo).w&0xffffu)); at_[7]=b2f((u16)((alo).w>>16));\
            at_[8]=b2f((u16)((ahi).x&0xffffu)); at_[9]=b2f((u16)((ahi).x>>16));\
            _Pragma("unroll")                                                  \
            for (int jj = 0; jj < 4; ++jj) {                                   \
                float ea_ = bb[jj];                                            \
                _Pragma("unroll")                                              \
                for (int k = 0; k < 10; ++k) ea_ = fmaf(at_[k], w[jj][k], ea_);\
                float v_ = hf_[jj] + ea_;                                      \
                acc[jj] += v_ > 0.f ? v_*(nm) : 0.f;                           \
            }                                                                  \
        } while(0)

        int p = s;
        for (; p + 4 <= e; p += 4) {
            int2 e0 = epack[p], e1 = epack[p+1], e2 = epack[p+2], e3 = epack[p+3];
            uint2 h0 = *reinterpret_cast<const uint2*>(&hx[(size_t)e0.x*EMB + f4]);
            uint2 h1 = *reinterpret_cast<const uint2*>(&hx[(size_t)e1.x*EMB + f4]);
            uint2 h2 = *reinterpret_cast<const uint2*>(&hx[(size_t)e2.x*EMB + f4]);
            uint2 h3 = *reinterpret_cast<const uint2*>(&hx[(size_t)e3.x*EMB + f4]);
            uint4 a0l = *reinterpret_cast<const uint4*>(&eab[(size_t)(p+0)*16]);
            uint4 a0h = *reinterpret_cast<const uint4*>(&eab[(size_t)(p+0)*16+8]);
            uint4 a1l = *reinterpret_cast<const uint4*>(&eab[(size_t)(p+1)*16]);
            uint4 a1h = *reinterpret_cast<const uint4*>(&eab[(size_t)(p+1)*16+8]);
            uint4 a2l = *reinterpret_cast<const uint4*>(&eab[(size_t)(p+2)*16]);
            uint4 a2h = *reinterpret_cast<const uint4*>(&eab[(size_t)(p+2)*16+8]);
            uint4 a3l = *reinterpret_cast<const uint4*>(&eab[(size_t)(p+3)*16]);
            uint4 a3h = *reinterpret_cast<const uint4*>(&eab[(size_t)(p+3)*16+8]);
            while (p+0 >= cend) FLUSH();
            CONSUME(__int_as_float(e0.y), h0, a0l, a0h);
            while (p+1 >= cend) FLUSH();
            CONSUME(__int_as_float(e1.y), h1, a1l, a1h);
            while (p+2 >= cend) FLUSH();
            CONSUME(__int_as_float(e2.y), h2, a2l, a2h);
            while (p+3 >= cend) FLUSH();
            CONSUME(__int_as_float(e3.y), h3, a3l, a3h);
        }
        for (; p < e; ++p) {
            int2 e0 = epack[p];
            uint2 h0 = *reinterpret_cast<const uint2*>(&hx[(size_t)e0.x*EMB + f4]);
            uint4 a0l = *reinterpret_cast<const uint4*>(&eab[(size_t)p*16]);
            uint4 a0h = *reinterpret_cast<const uint4*>(&eab[(size_t)p*16+8]);
            while (p >= cend) FLUSH();
            CONSUME(__int_as_float(e0.y), h0, a0l, a0h);
        }
        while (jn < GFB) FLUSH();
        #undef FLUSH
        #undef CONSUME
    }

    #pragma unroll
    for (int j = 0; j < 4; ++j) {
        red[wid][f4+j]     = sacc[j];
        red[wid][256+f4+j] = s2acc[j];
    }
    __syncthreads();
    int tt = threadIdx.x;
    float a0 = red[0][tt] + red[1][tt] + red[2][tt] + red[3][tt];
    float a1 = red[0][256+tt] + red[1][256+tt] + red[2][256+tt] + red[3][256+tt];
    atomicAdd(&stats[tt], a0);
    atomicAdd(&stats[256+tt], a1);
}

// ---------------- mean pool (applies final BN inline), 128 nodes/block --------
__global__ __launch_bounds__(256) void pool_kernel(const u16* __restrict__ t,
        const int* __restrict__ batch, const float* __restrict__ stats5,
        const float* __restrict__ gamma5, const float* __restrict__ beta5,
        float* __restrict__ psum, float* __restrict__ pcnt, int N)
{
    int tid = threadIdx.x;
    int half = tid >> 7;
    int pp = tid & 127;
    const u32* t32 = (const u32*)t;
    float sc0, sh0, sc1, sh1;
    bnsc_f(stats5, gamma5, beta5, 2*pp,   sc0, sh0);
    bnsc_f(stats5, gamma5, beta5, 2*pp+1, sc1, sh1);
    int n0 = blockIdx.x * 128;
    int n1 = min(n0 + 128, N);
    int start = n0 + half;
    if (start >= n1) return;
    int cur = batch[start];
    float a0 = 0.f, a1 = 0.f;
    int cnt = 0;
    for (int n = start; n < n1; n += 2) {
        int gb = batch[n];
        if (gb != cur) {
            atomicAdd(&psum[(size_t)cur*EMB + 2*pp],   a0);
            atomicAdd(&psum[(size_t)cur*EMB + 2*pp+1], a1);
            if (pp == 0) atomicAdd(&pcnt[cur], (float)cnt);
            a0 = a1 = 0.f; cnt = 0; cur = gb;
        }
        u32 v = t32[(size_t)n*128 + pp];
        a0 += fmaf(b2f((u16)(v & 0xffffu)), sc0, sh0);
        a1 += fmaf(b2f((u16)(v >> 16)),     sc1, sh1);
        ++cnt;
    }
    atomicAdd(&psum[(size_t)cur*EMB + 2*pp],   a0);
    atomicAdd(&psum[(size_t)cur*EMB + 2*pp+1], a1);
    if (pp == 0) atomicAdd(&pcnt[cur], (float)cnt);
}

// ---------------- g = psum/cnt  (bf16 out) ----------------
__global__ void pool2g(const float* __restrict__ psum, const float* __restrict__ pcnt,
        u16* __restrict__ gbf)
{
    int i = blockIdx.x*256 + threadIdx.x;
    if (i < NG*128) {
        int g = i >> 7, p2 = (i & 127)*2;
        float invc = 1.0f / fmaxf(pcnt[g], 1.0f);
        u32 pk = (u32)f2b(psum[(size_t)g*EMB + p2] * invc)
               | ((u32)f2b(psum[(size_t)g*EMB + p2 + 1] * invc) << 16);
        ((u32*)gbf)[i] = pk;
    }
}

// ---------------- head GEMM: C = relu(A @ W.T + b), N=128, K param ------------
__global__ __launch_bounds__(256) void gemm_head(const u16* __restrict__ A,
        const u16* __restrict__ W, const float* __restrict__ bias,
        u16* __restrict__ C, int M, int K)
{
    __shared__ u16 As[128*64];
    __shared__ u16 Bs[128*64];
    const int tid  = threadIdx.x;
    const int wid  = tid >> 6;
    const int lane = tid & 63;
    const int wr = wid >> 1, wc = wid & 1;
    const int m0 = blockIdx.x * 128;
    f32x4 acc[4][4] = {};
    for (int k0 = 0; k0 < K; k0 += 64) {
        #pragma unroll
        for (int i = 0; i < 4; ++i) {
            int L = tid + i*256;
            int rowi = L >> 3, ch = L & 7;
            int sw = ch ^ (rowi & 7);
            int gr = m0 + rowi; gr = gr < M ? gr : M-1;
            uint4 va = *reinterpret_cast<const uint4*>(&A[(size_t)gr*K + k0 + ch*8]);
            *reinterpret_cast<uint4*>(&As[(rowi*8 + sw)*8]) = va;
            uint4 vb = *reinterpret_cast<const uint4*>(&W[(size_t)rowi*K + k0 + ch*8]);
            *reinterpret_cast<uint4*>(&Bs[(rowi*8 + sw)*8]) = vb;
        }
        __syncthreads();
        const int c = lane >> 4;
        const int rl = lane & 15;
        #pragma unroll
        for (int kt = 0; kt < 2; ++kt) {
            bf16x8 af[4], bfr[4];
            #pragma unroll
            for (int f = 0; f < 4; ++f) {
                int ra = wr*64 + f*16 + rl;
                int cha = (kt*4 + c) ^ (ra & 7);
                af[f] = *reinterpret_cast<const bf16x8*>(&As[(ra*8 + cha)*8]);
                int rb = wc*64 + f*16 + rl;
                int chb = (kt*4 + c) ^ (rb & 7);
                bfr[f] = *reinterpret_cast<const bf16x8*>(&Bs[(rb*8 + chb)*8]);
            }
            #pragma unroll
            for (int fm = 0; fm < 4; ++fm)
                #pragma unroll
                for (int fn = 0; fn < 4; ++fn)
                    acc[fm][fn] = __builtin_amdgcn_mfma_f32_16x16x32_bf16(
                        af[fm], bfr[fn], acc[fm][fn], 0, 0, 0);
        }
        __syncthreads();
    }
    const int cn = lane & 15, rq = lane >> 4;
    #pragma unroll
    for (int fn = 0; fn < 4; ++fn) {
        int n = wc*64 + fn*16 + cn;
        float bb = bias[n];
        #pragma unroll
        for (int fm = 0; fm < 4; ++fm) {
            #pragma unroll
            for (int r = 0; r < 4; ++r) {
                int m = m0 + wr*64 + fm*16 + rq*4 + r;
                if (m < M) C[(size_t)m*128 + n] = f2b(fmaxf(acc[fm][fn][r] + bb, 0.f));
            }
        }
    }
}

// ---------------- head final: out[g] = dot(h2[g], p3W) + p3b ----------------
__global__ __launch_bounds__(256) void head_final(const u16* __restrict__ h2,
        const float* __restrict__ p3W, const float* __restrict__ p3b,
        float* __restrict__ out, int G)
{
    int tid = blockIdx.x*256 + threadIdx.x;
    int g = tid >> 4, sub = tid & 15;
    if (g >= G) return;
    uint4 v = *reinterpret_cast<const uint4*>(&h2[(size_t)g*128 + sub*8]);
    u32 wv[4] = {v.x, v.y, v.z, v.w};
    float s = 0.f;
    #pragma unroll
    for (int j = 0; j < 4; ++j) {
        s = fmaf(b2f((u16)(wv[j] & 0xffffu)), p3W[sub*8 + 2*j],   s);
        s = fmaf(b2f((u16)(wv[j] >> 16)),     p3W[sub*8 + 2*j+1], s);
    }
    s += __shfl_down(s, 8, 16);
    s += __shfl_down(s, 4, 16);
    s += __shfl_down(s, 2, 16);
    s += __shfl_down(s, 1, 16);
    if (sub == 0) out[g] = s + p3b[0];
}

extern "C" void kernel_launch(void* const* d_in, const int* in_sizes, int n_in,
                              void* d_out, int out_size, void* d_ws, size_t ws_size,
                              hipStream_t stream)
{
    const float* x     = (const float*)d_in[0];
    const int*   eidx  = (const int*)d_in[1];
    const float* eattr = (const float*)d_in[2];
    const int*   batch = (const int*)d_in[3];
    const float* xW    = (const float*)d_in[4];
    const float* xb    = (const float*)d_in[5];
    const float* eW    = (const float*)d_in[6];
    const float* eb    = (const float*)d_in[7];
    const float* gcnW  = (const float*)d_in[8];
    const float* gcnb  = (const float*)d_in[9];
    const float* rootE = (const float*)d_in[10];
    const float* bng   = (const float*)d_in[11];
    const float* bnb   = (const float*)d_in[12];
    const float* p1W   = (const float*)d_in[13];
    const float* p1b   = (const float*)d_in[14];
    const float* p2W   = (const float*)d_in[15];
    const float* p2b   = (const float*)d_in[16];
    const float* p3W   = (const float*)d_in[17];
    const float* p3b   = (const float*)d_in[18];
    float* out = (float*)d_out;

    const int* row = eidx;
    const int* col = eidx + NE;

    const size_t HSZ = (size_t)NN * EMB;            // 25.6M elements
    const int NWB = 5*EMB*EMB;                      // 327680

    // ---- ws layout ----
    char* p = (char*)d_ws;
    u16* t   = (u16*)p;            p += HSZ*2;      // pre-BN state
    u16* hx  = (u16*)p;            p += HSZ*2;      // GEMM output
    u16* Wb  = (u16*)p;            p += (size_t)NWB*2;
    float* eWt = (float*)p;        p += 2560*4;
    char* zbase = p;                                 // prologue-zeroed region
    int* rcnt   = (int*)p;         p += (size_t)NN*4;
    int* ccnt   = (int*)p;         p += (size_t)NN*4;
    int* fill   = (int*)p;         p += (size_t)NN*4;
    float* stats= (float*)p;       p += (size_t)NLAYERS*512*4;
    float* psum = (float*)p;       p += (size_t)NG*EMB*4;
    float* pcnt = (float*)p;       p += (size_t)NG*4;
    size_t zbytes = (size_t)(p - zbase);
    float* dinv = (float*)p;       p += (size_t)NN*4;
    float* invdg= (float*)p;       p += (size_t)NN*4;
    int* coff   = (int*)p;         p += (size_t)(NN+1)*4;
    int* bsum   = (int*)p;         p += 512*4;
    int* bbase  = (int*)p;         p += 512*4;
    int2* epack = (int2*)p;        p += (size_t)NE*8;
    u16* eab    = (u16*)p;         p += (size_t)NE*16*2;
    u16* gbf    = (u16*)p;         p += (size_t)NG*EMB*2;
    u16* h1b    = (u16*)p;         p += (size_t)NG*128*2;
    u16* h2b    = (u16*)p;         p += (size_t)NG*128*2;
    u16* Wh1    = (u16*)p;         p += (size_t)128*256*2;
    u16* Wh2    = (u16*)p;         p += (size_t)128*128*2;
    size_t NEED = (size_t)(p - (char*)d_ws);
    if (ws_size < NEED) return;    // fail absmax cleanly instead of faulting

    hipMemsetAsync(zbase, 0, zbytes, stream);

    const int NBS = (NN + 255)/256;

    embed_x<<<NN/XNB, 256, 0, stream>>>(x, xW, xb, t);
    wconv<<<(NWB+255)/256, 256, 0, stream>>>(gcnW, Wb, NWB);
    wconv<<<(128*256+255)/256, 256, 0, stream>>>(p1W, Wh1, 128*256);
    wconv<<<(128*128+255)/256, 256, 0, stream>>>(p2W, Wh2, 128*128);
    ewt_kernel<<<10, 256, 0, stream>>>(eW, eWt);
    hist_kernel<<<(NE+255)/256, 256, 0, stream>>>(row, col, rcnt, ccnt, NE);
    deg_fin<<<NBS, 256, 0, stream>>>(rcnt, dinv, invdg, NN);
    scan1<<<NBS, 256, 0, stream>>>(ccnt, bsum, NN);
    scan2<<<1, 512, 0, stream>>>(bsum, bbase, coff, NBS);
    scan3<<<NBS, 256, 0, stream>>>(ccnt, bbase, coff, NN);
    csr_fill<<<(NE+255)/256, 256, 0, stream>>>(row, col, eattr, coff, dinv, fill,
                                               epack, eab, NE);

    for (int l = 0; l < NLAYERS; ++l) {
        const u16*   Wl = Wb + (size_t)l*EMB*EMB;
        const float* bl = gcnb + (size_t)l*EMB;
        const float* rl = rootE + (size_t)l*EMB;
        const float* stPrev = stats + (size_t)(l > 0 ? l-1 : 0)*512;
        const float* gmPrev = bng + (size_t)(l > 0 ? l-1 : 0)*EMB;
        const float* btPrev = bnb + (size_t)(l > 0 ? l-1 : 0)*EMB;
        int doBN = (l > 0) ? 1 : 0;
        gemm_mfma<<<(NN+63)/64, 256, 0, stream>>>(t, Wl, bl, stPrev, gmPrev,
                                                  btPrev, doBN, hx, NN);
        gather_combine_w<<<1536, 256, 0, stream>>>(epack, eab, coff, eWt, eb,
                hx, rl, invdg, stPrev, gmPrev, btPrev, doBN, t, stats + l*512, NN);
    }

    pool_kernel<<<(NN+127)/128, 256, 0, stream>>>(t, batch,
            stats + (size_t)(NLAYERS-1)*512,
            bng + (size_t)(NLAYERS-1)*EMB, bnb + (size_t)(NLAYERS-1)*EMB,
            psum, pcnt, NN);
    pool2g<<<(NG*128+255)/256, 256, 0, stream>>>(psum, pcnt, gbf);
    gemm_head<<<NG/128, 256, 0, stream>>>(gbf, Wh1, p1b, h1b, NG, 256);
    gemm_head<<<NG/128, 256, 0, stream>>>(h1b, Wh2, p2b, h2b, NG, 128);
    head_final<<<(NG*16+255)/256, 256, 0, stream>>>(h2b, p3W, p3b, out, NG);
}

// Round 19
// 862.468 us; speedup vs baseline: 2.2478x; 2.2478x over previous
//
#include <hip/hip_runtime.h>
#include <hip/hip_bf16.h>

#define NN 100000
#define NE 300000
#define NG 4096
#define EMB 256
#define NLAYERS 5

typedef unsigned short u16;
typedef unsigned int u32;

typedef short bf16x8 __attribute__((ext_vector_type(8)));
typedef float f32x4 __attribute__((ext_vector_type(4)));

__device__ __forceinline__ float b2f(u16 u){
    union { float f; u32 i; } v; v.i = ((u32)u) << 16; return v.f;
}
__device__ __forceinline__ u16 f2b(float f){
    __hip_bfloat16 h = __float2bfloat16(f);   // RNE
    union { __hip_bfloat16 h; u16 u; } v; v.h = h; return v.u;
}
// inline BN finalize: sc/sh for feature f from raw sums
__device__ __forceinline__ void bnsc_f(const float* __restrict__ stats,
        const float* __restrict__ gamma, const float* __restrict__ beta,
        int f, float& sc, float& sh)
{
    const float inv = 1.0f / (float)NN;
    float mean = stats[f] * inv;
    float var  = stats[256+f] * inv - mean*mean;
    float is = rsqrtf(var + 1e-5f);
    sc = gamma[f] * is;
    sh = fmaf(-mean, sc, beta[f]);
}

// ---------------- x embedding: t = x @ xW.T + xb  (bf16 out, raw/pre-BN) ------
#define XNB 32
__global__ __launch_bounds__(256) void embed_x(const float* __restrict__ x,
        const float* __restrict__ W, const float* __restrict__ b,
        u16* __restrict__ t)
{
    __shared__ float sW[256][41];
    __shared__ float sx[XNB][40];
    int tid = threadIdx.x;
    for (int i = tid; i < 256*40; i += 256) sW[i/40][i%40] = W[i];
    int n0 = blockIdx.x * XNB;      // 100000 = 3125*32 exact
    for (int i = tid; i < XNB*40; i += 256) {
        int j = i/40, k = i%40;
        sx[j][k] = x[(size_t)(n0+j)*40 + k];
    }
    __syncthreads();
    float bb = b[tid];
    for (int j = 0; j < XNB; ++j) {
        float a = bb;
        #pragma unroll
        for (int k = 0; k < 40; ++k) a = fmaf(sW[tid][k], sx[j][k], a);
        t[(size_t)(n0+j)*EMB + tid] = f2b(a);
    }
}

// ---------------- W -> bf16 ----------------
__global__ void wconv(const float* __restrict__ W, u16* __restrict__ Wb, int n)
{
    int i = blockIdx.x*256 + threadIdx.x;
    if (i < n) Wb[i] = f2b(W[i]);
}

// ---------------- eW transpose: eWt[k*256+f] = eW[f*10+k] ----------------
__global__ void ewt_kernel(const float* __restrict__ eW, float* __restrict__ eWt)
{
    int i = blockIdx.x*256 + threadIdx.x;
    if (i < 2560) { int f = i/10, k = i%10; eWt[k*256 + f] = eW[i]; }
}

// ---------------- histograms ----------------
__global__ void hist_kernel(const int* __restrict__ row, const int* __restrict__ col,
        int* __restrict__ rcnt, int* __restrict__ ccnt, int E)
{
    int e = blockIdx.x*256 + threadIdx.x;
    if (e < E) {
        atomicAdd(&rcnt[row[e]], 1);
        atomicAdd(&ccnt[col[e]], 1);
    }
}

__global__ void deg_fin(const int* __restrict__ rcnt, float* __restrict__ dinv,
                        float* __restrict__ invdg, int N)
{
    int n = blockIdx.x*256 + threadIdx.x;
    if (n < N) {
        float d = (float)rcnt[n] + 1.0f;
        dinv[n]  = rsqrtf(d);
        invdg[n] = 1.0f/d;
    }
}

// ---------------- prefix scan (3 kernels) ----------------
__global__ void scan1(const int* __restrict__ cnt, int* __restrict__ bsum, int N)
{
    __shared__ int sh[256];
    int t = threadIdx.x, i = blockIdx.x*256 + t;
    sh[t] = (i < N) ? cnt[i] : 0;
    __syncthreads();
    for (int off = 128; off > 0; off >>= 1) {
        if (t < off) sh[t] += sh[t+off];
        __syncthreads();
    }
    if (t == 0) bsum[blockIdx.x] = sh[0];
}

__global__ __launch_bounds__(512) void scan2(const int* __restrict__ bsum,
        int* __restrict__ bbase, int* __restrict__ coff, int nb)
{
    __shared__ int a[512], b[512];
    int t = threadIdx.x;
    a[t] = (t < nb) ? bsum[t] : 0;
    __syncthreads();
    int* src = a; int* dst = b;
    for (int off = 1; off < 512; off <<= 1) {
        dst[t] = (t >= off) ? src[t-off] + src[t] : src[t];
        __syncthreads();
        int* tmp = src; src = dst; dst = tmp;
    }
    bbase[t] = t ? src[t-1] : 0;
    if (t == 0) coff[NN] = NE;
}

__global__ void scan3(const int* __restrict__ cnt, const int* __restrict__ bbase,
        int* __restrict__ coff, int N)
{
    __shared__ int a[256], b[256];
    int t = threadIdx.x, i = blockIdx.x*256 + t;
    a[t] = (i < N) ? cnt[i] : 0;
    __syncthreads();
    int* src = a; int* dst = b;
    for (int off = 1; off < 256; off <<= 1) {
        dst[t] = (t >= off) ? src[t-off] + src[t] : src[t];
        __syncthreads();
        int* tmp = src; src = dst; dst = tmp;
    }
    if (i < N) coff[i] = bbase[blockIdx.x] + (t ? src[t-1] : 0);
}

// CSR fill: epack[p]={row, norm-bits}; eab[p][16] = bf16 eattr (10 used)
__global__ void csr_fill(const int* __restrict__ row, const int* __restrict__ col,
        const float* __restrict__ eattr, const int* __restrict__ coff,
        const float* __restrict__ dinv, int* __restrict__ fill,
        int2* __restrict__ epack, u16* __restrict__ eab, int E)
{
    int e = blockIdx.x*256 + threadIdx.x;
    if (e < E) {
        int c = col[e], r = row[e];
        int p = coff[c] + atomicAdd(&fill[c], 1);
        int2 ep; ep.x = r; ep.y = __float_as_int(dinv[r] * dinv[c]);
        epack[p] = ep;
        #pragma unroll
        for (int k = 0; k < 10; ++k) eab[(size_t)p*16 + k] = f2b(eattr[(size_t)e*10 + k]);
        #pragma unroll
        for (int k = 10; k < 16; ++k) eab[(size_t)p*16 + k] = 0;
    }
}

// ---------------- MFMA GEMM v6: BM=64, 256 thr, 4 waves (1x4), A dbuf-LDS -----
// C[m][o] = sum_k affine(A[m][k]) * Wb[o][k] + bias[o]
#define CS2 264   // epilogue row stride (u16), 256 cols + 8 pad; 132 words == 4 mod 32 banks
__global__ __launch_bounds__(256, 4) void gemm_mfma(const u16* __restrict__ A,
        const u16* __restrict__ Wb, const float* __restrict__ bias,
        const float* __restrict__ stats, const float* __restrict__ gamma,
        const float* __restrict__ beta, int doBN,
        u16* __restrict__ C, int M)
{
    __shared__ __align__(16) char smem[33792];   // As0 8K | As1 8K | sc/sh 2K; Cs 33792 overlays
    u16* As0 = (u16*)smem;
    u16* As1 = (u16*)(smem + 8192);
    float* scS = (float*)(smem + 16384);
    float* shS = scS + 256;
    const int tid = threadIdx.x;
    if (doBN) {
        float s, h; bnsc_f(stats, gamma, beta, tid, s, h);
        scS[tid] = s; shS[tid] = h;
    }
    const int lane = tid & 63;
    const int wn = tid >> 6;                 // 0..3: 64-col panel
    const int m0 = blockIdx.x * 64;
    const int r8 = tid >> 3;                 // 0..31
    const int ch = tid & 7;
    const int sw = ch ^ (r8 & 7);            // (r8+32)&7 == r8&7
    const int ga0 = min(m0 + r8,      M-1);
    const int ga1 = min(m0 + r8 + 32, M-1);
    const int c  = lane >> 4;
    const int rl = lane & 15;
    const int nb0 = wn*64 + rl;              // B row base for this lane

    uint4 ra0, ra1;
    #define LOADK(k0) do {                                                     \
        ra0 = *reinterpret_cast<const uint4*>(&A[(size_t)ga0*256 + (k0) + ch*8]); \
        ra1 = *reinterpret_cast<const uint4*>(&A[(size_t)ga1*256 + (k0) + ch*8]); \
    } while(0)

    #define STAGE(dst, k0v) do {                                               \
        uint4 va0 = ra0, va1 = ra1;                                            \
        if (doBN) {                                                            \
            int kk = (k0v) + ch*8;                                             \
            u32 w0[4] = {va0.x, va0.y, va0.z, va0.w};                          \
            u32 w1[4] = {va1.x, va1.y, va1.z, va1.w};                          \
            _Pragma("unroll")                                                  \
            for (int j = 0; j < 4; ++j) {                                      \
                float l0 = b2f((u16)(w0[j] & 0xffffu)), h0 = b2f((u16)(w0[j] >> 16)); \
                float l1 = b2f((u16)(w1[j] & 0xffffu)), h1 = b2f((u16)(w1[j] >> 16)); \
                float s0 = scS[kk+2*j], s1 = scS[kk+2*j+1];                    \
                float b0 = shS[kk+2*j], b1 = shS[kk+2*j+1];                    \
                l0 = fmaxf(fmaf(l0, s0, b0), 0.f); h0 = fmaxf(fmaf(h0, s1, b1), 0.f); \
                l1 = fmaxf(fmaf(l1, s0, b0), 0.f); h1 = fmaxf(fmaf(h1, s1, b1), 0.f); \
                w0[j] = (u32)f2b(l0) | ((u32)f2b(h0) << 16);                   \
                w1[j] = (u32)f2b(l1) | ((u32)f2b(h1) << 16);                   \
            }                                                                  \
            va0.x=w0[0]; va0.y=w0[1]; va0.z=w0[2]; va0.w=w0[3];                \
            va1.x=w1[0]; va1.y=w1[1]; va1.z=w1[2]; va1.w=w1[3];                \
        }                                                                      \
        *reinterpret_cast<uint4*>(&(dst)[((r8     )*8 + sw)*8]) = va0;         \
        *reinterpret_cast<uint4*>(&(dst)[((r8 + 32)*8 + sw)*8]) = va1;         \
    } while(0)

    f32x4 acc[4][4] = {};
    #define KSTEP(cur, k0v) do {                                               \
        _Pragma("unroll")                                                      \
        for (int kt = 0; kt < 2; ++kt) {                                       \
            bf16x8 af[4], bfr[4];                                              \
            _Pragma("unroll")                                                  \
            for (int f = 0; f < 4; ++f) {                                      \
                bfr[f] = *reinterpret_cast<const bf16x8*>(                     \
                    &Wb[(size_t)(nb0 + f*16)*256 + (k0v) + (kt*4 + c)*8]);     \
                int rA = f*16 + rl;                                            \
                int cha = (kt*4 + c) ^ (rA & 7);                               \
                af[f] = *reinterpret_cast<const bf16x8*>(&(cur)[(rA*8 + cha)*8]); \
            }                                                                  \
            _Pragma("unroll")                                                  \
            for (int fm = 0; fm < 4; ++fm)                                     \
                _Pragma("unroll")                                              \
                for (int fn = 0; fn < 4; ++fn)                                 \
                    acc[fm][fn] = __builtin_amdgcn_mfma_f32_16x16x32_bf16(     \
                        af[fm], bfr[fn], acc[fm][fn], 0, 0, 0);                \
        }                                                                      \
    } while(0)

    LOADK(0);
    if (doBN) __syncthreads();   // scS/shS visible before first affine
    STAGE(As0, 0);
    LOADK(64);
    __syncthreads();             // As0 visible
    STAGE(As1, 64); LOADK(128);
    KSTEP(As0, 0);
    __syncthreads();
    STAGE(As0, 128); LOADK(192);
    KSTEP(As1, 64);
    __syncthreads();
    STAGE(As1, 192);
    KSTEP(As0, 128);
    __syncthreads();
    KSTEP(As1, 192);
    __syncthreads();             // before Cs overlays As/scsh
    #undef LOADK
    #undef STAGE
    #undef KSTEP

    // ---- epilogue: single-pass LDS bounce -> coalesced uint4 stores ----
    u16* Cs = (u16*)smem;        // 64 x CS2 u16 = 33792 B
    const int cn = lane & 15, rq = lane >> 4;
    const int cl0 = wn*64;
    #pragma unroll
    for (int fn = 0; fn < 4; ++fn) {
        int n = cl0 + fn*16 + cn;
        float bb = bias[n];
        #pragma unroll
        for (int fm = 0; fm < 4; ++fm) {
            int rbase = fm*16 + rq*4;
            #pragma unroll
            for (int r = 0; r < 4; ++r)
                Cs[(rbase + r)*CS2 + n] = f2b(acc[fm][fn][r] + bb);
        }
    }
    __syncthreads();
    #pragma unroll
    for (int it = 0; it < 8; ++it) {
        int idx = tid + it*256;              // 0..2047
        int rowi = idx >> 5;                 // 0..63
        int c8  = (idx & 31) * 8;            // 0..248
        int m = m0 + rowi;
        if (m < M)
            *reinterpret_cast<uint4*>(&C[(size_t)m*256 + c8]) =
                *reinterpret_cast<const uint4*>(&Cs[rowi*CS2 + c8]);
    }
}

// ================= gather+combine: on-the-fly edge MLP (round-12 best) ========
#define GFB 4
#define NGROUPS (NN/GFB)
__global__ __launch_bounds__(256) void gather_combine_w(const int2* __restrict__ epack,
        const u16* __restrict__ eab, const int* __restrict__ coff,
        const float* __restrict__ eWt, const float* __restrict__ ebv,
        const u16* __restrict__ hx, const float* __restrict__ rootv,
        const float* __restrict__ invdg, const float* __restrict__ statsPrev,
        const float* __restrict__ gammaPrev, const float* __restrict__ betaPrev,
        int doBN, u16* __restrict__ t, float* __restrict__ stats, int N)
{
    __shared__ float red[4][512];
    const int wid = threadIdx.x >> 6, lane = threadIdx.x & 63;
    const int f4 = lane*4;
    float w[4][10], bb[4];
    #pragma unroll
    for (int k = 0; k < 10; ++k) {
        float4 wv = *reinterpret_cast<const float4*>(&eWt[k*256 + f4]);
        w[0][k] = wv.x; w[1][k] = wv.y; w[2][k] = wv.z; w[3][k] = wv.w;
    }
    { float4 bv = *reinterpret_cast<const float4*>(&ebv[f4]);
      bb[0]=bv.x; bb[1]=bv.y; bb[2]=bv.z; bb[3]=bv.w; }
    float4 root = *reinterpret_cast<const float4*>(&rootv[f4]);
    float sc[4] = {1,1,1,1}, sh[4] = {0,0,0,0};
    if (doBN) {
        #pragma unroll
        for (int j = 0; j < 4; ++j)
            bnsc_f(statsPrev, gammaPrev, betaPrev, f4+j, sc[j], sh[j]);
    }
    float sacc[4] = {0,0,0,0}, s2acc[4] = {0,0,0,0};

    for (int g = blockIdx.x*4 + wid; g < NGROUPS; g += gridDim.x*4) {
        const int nb = g*GFB;
        int c1 = coff[nb+1], c2 = coff[nb+2], c3 = coff[nb+3], c4 = coff[nb+4];
        int s = coff[nb], e = c4;
        int jn = 0, cend = c1;
        float acc[4] = {0,0,0,0};

        #define FLUSH() do {                                                   \
            int n_ = nb + jn;                                                  \
            size_t idx_ = (size_t)n_*EMB + f4;                                 \
            uint2 hv_ = *reinterpret_cast<const uint2*>(&t[idx_]);             \
            uint2 xv_ = *reinterpret_cast<const uint2*>(&hx[idx_]);            \
            float id_ = invdg[n_];                                             \
            float hh_[4] = { b2f((u16)(hv_.x&0xffffu)), b2f((u16)(hv_.x>>16)), \
                             b2f((u16)(hv_.y&0xffffu)), b2f((u16)(hv_.y>>16)) };\
            float xx_[4] = { b2f((u16)(xv_.x&0xffffu)), b2f((u16)(xv_.x>>16)), \
                             b2f((u16)(xv_.y&0xffffu)), b2f((u16)(xv_.y>>16)) };\
            float rt_[4] = { root.x, root.y, root.z, root.w };                 \
            u16 ov_[4];                                                        \
            _Pragma("unroll")                                                  \
            for (int jj = 0; jj < 4; ++jj) {                                   \
                float hin_ = hh_[jj];                                          \
                if (doBN) hin_ = fmaxf(fmaf(hin_, sc[jj], sh[jj]), 0.f);       \
                float rv_ = xx_[jj] + rt_[jj];                                 \
                rv_ = rv_ > 0.f ? rv_ : 0.f;                                   \
                float tv_ = hin_ + acc[jj] + rv_*id_;                          \
                ov_[jj] = f2b(tv_);                                            \
                sacc[jj] += tv_; s2acc[jj] += tv_*tv_;                         \
                acc[jj] = 0.f;                                                 \
            }                                                                  \
            uint2 o_; o_.x = (u32)ov_[0] | ((u32)ov_[1]<<16);                  \
            o_.y = (u32)ov_[2] | ((u32)ov_[3]<<16);                            \
            *reinterpret_cast<uint2*>(&t[idx_]) = o_;                          \
            ++jn; cend = (jn==1) ? c2 : (jn==2) ? c3 : c4;                     \
        } while(0)

        #define CONSUME(nm, hvv, alo, ahi) do {                                \
            float hf_[4] = { b2f((u16)((hvv).x&0xffffu)), b2f((u16)((hvv).x>>16)),\
                             b2f((u16)((hvv).y&0xffffu)), b2f((u16)((hvv).y>>16)) };\
            float at_[10];                                                     \
            at_[0]=b2f((u16)((alo).x&0xffffu)); at_[1]=b2f((u16)((alo).x>>16));\
            at_[2]=b2f((u16)((alo).y&0xffffu)); at_[3]=b2f((u16)((alo).y>>16));\
            at_[4]=b2f((u16)((alo).z&0xffffu)); at_[5]=b2f((u16)((alo).z>>16));\
            at_[6]=b2f((u16)((alo).w&0xffffu)); at_[7]=b2f((u16)((alo).w>>16));\
            at_[8]=b2f((u16)((ahi).x&0xffffu)); at_[9]=b2f((u16)((ahi).x>>16));\
            _Pragma("unroll")                                                  \
            for (int jj = 0; jj < 4; ++jj) {                                   \
                float ea_ = bb[jj];                                            \
                _Pragma("unroll")                                              \
                for (int k = 0; k < 10; ++k) ea_ = fmaf(at_[k], w[jj][k], ea_);\
                float v_ = hf_[jj] + ea_;                                      \
                acc[jj] += v_ > 0.f ? v_*(nm) : 0.f;                           \
            }                                                                  \
        } while(0)

        int p = s;
        for (; p + 4 <= e; p += 4) {
            int2 e0 = epack[p], e1 = epack[p+1], e2 = epack[p+2], e3 = epack[p+3];
            uint2 h0 = *reinterpret_cast<const uint2*>(&hx[(size_t)e0.x*EMB + f4]);
            uint2 h1 = *reinterpret_cast<const uint2*>(&hx[(size_t)e1.x*EMB + f4]);
            uint2 h2 = *reinterpret_cast<const uint2*>(&hx[(size_t)e2.x*EMB + f4]);
            uint2 h3 = *reinterpret_cast<const uint2*>(&hx[(size_t)e3.x*EMB + f4]);
            uint4 a0l = *reinterpret_cast<const uint4*>(&eab[(size_t)(p+0)*16]);
            uint4 a0h = *reinterpret_cast<const uint4*>(&eab[(size_t)(p+0)*16+8]);
            uint4 a1l = *reinterpret_cast<const uint4*>(&eab[(size_t)(p+1)*16]);
            uint4 a1h = *reinterpret_cast<const uint4*>(&eab[(size_t)(p+1)*16+8]);
            uint4 a2l = *reinterpret_cast<const uint4*>(&eab[(size_t)(p+2)*16]);
            uint4 a2h = *reinterpret_cast<const uint4*>(&eab[(size_t)(p+2)*16+8]);
            uint4 a3l = *reinterpret_cast<const uint4*>(&eab[(size_t)(p+3)*16]);
            uint4 a3h = *reinterpret_cast<const uint4*>(&eab[(size_t)(p+3)*16+8]);
            while (p+0 >= cend) FLUSH();
            CONSUME(__int_as_float(e0.y), h0, a0l, a0h);
            while (p+1 >= cend) FLUSH();
            CONSUME(__int_as_float(e1.y), h1, a1l, a1h);
            while (p+2 >= cend) FLUSH();
            CONSUME(__int_as_float(e2.y), h2, a2l, a2h);
            while (p+3 >= cend) FLUSH();
            CONSUME(__int_as_float(e3.y), h3, a3l, a3h);
        }
        for (; p < e; ++p) {
            int2 e0 = epack[p];
            uint2 h0 = *reinterpret_cast<const uint2*>(&hx[(size_t)e0.x*EMB + f4]);
            uint4 a0l = *reinterpret_cast<const uint4*>(&eab[(size_t)p*16]);
            uint4 a0h = *reinterpret_cast<const uint4*>(&eab[(size_t)p*16+8]);
            while (p >= cend) FLUSH();
            CONSUME(__int_as_float(e0.y), h0, a0l, a0h);
        }
        while (jn < GFB) FLUSH();
        #undef FLUSH
        #undef CONSUME
    }

    #pragma unroll
    for (int j = 0; j < 4; ++j) {
        red[wid][f4+j]     = sacc[j];
        red[wid][256+f4+j] = s2acc[j];
    }
    __syncthreads();
    int tt = threadIdx.x;
    float a0 = red[0][tt] + red[1][tt] + red[2][tt] + red[3][tt];
    float a1 = red[0][256+tt] + red[1][256+tt] + red[2][256+tt] + red[3][256+tt];
    atomicAdd(&stats[tt], a0);
    atomicAdd(&stats[256+tt], a1);
}

// ---------------- mean pool (applies final BN inline), 128 nodes/block --------
__global__ __launch_bounds__(256) void pool_kernel(const u16* __restrict__ t,
        const int* __restrict__ batch, const float* __restrict__ stats5,
        const float* __restrict__ gamma5, const float* __restrict__ beta5,
        float* __restrict__ psum, float* __restrict__ pcnt, int N)
{
    int tid = threadIdx.x;
    int half = tid >> 7;
    int pp = tid & 127;
    const u32* t32 = (const u32*)t;
    float sc0, sh0, sc1, sh1;
    bnsc_f(stats5, gamma5, beta5, 2*pp,   sc0, sh0);
    bnsc_f(stats5, gamma5, beta5, 2*pp+1, sc1, sh1);
    int n0 = blockIdx.x * 128;
    int n1 = min(n0 + 128, N);
    int start = n0 + half;
    if (start >= n1) return;
    int cur = batch[start];
    float a0 = 0.f, a1 = 0.f;
    int cnt = 0;
    for (int n = start; n < n1; n += 2) {
        int gb = batch[n];
        if (gb != cur) {
            atomicAdd(&psum[(size_t)cur*EMB + 2*pp],   a0);
            atomicAdd(&psum[(size_t)cur*EMB + 2*pp+1], a1);
            if (pp == 0) atomicAdd(&pcnt[cur], (float)cnt);
            a0 = a1 = 0.f; cnt = 0; cur = gb;
        }
        u32 v = t32[(size_t)n*128 + pp];
        a0 += fmaf(b2f((u16)(v & 0xffffu)), sc0, sh0);
        a1 += fmaf(b2f((u16)(v >> 16)),     sc1, sh1);
        ++cnt;
    }
    atomicAdd(&psum[(size_t)cur*EMB + 2*pp],   a0);
    atomicAdd(&psum[(size_t)cur*EMB + 2*pp+1], a1);
    if (pp == 0) atomicAdd(&pcnt[cur], (float)cnt);
}

// ---------------- g = psum/cnt  (bf16 out) ----------------
__global__ void pool2g(const float* __restrict__ psum, const float* __restrict__ pcnt,
        u16* __restrict__ gbf)
{
    int i = blockIdx.x*256 + threadIdx.x;
    if (i < NG*128) {
        int g = i >> 7, p2 = (i & 127)*2;
        float invc = 1.0f / fmaxf(pcnt[g], 1.0f);
        u32 pk = (u32)f2b(psum[(size_t)g*EMB + p2] * invc)
               | ((u32)f2b(psum[(size_t)g*EMB + p2 + 1] * invc) << 16);
        ((u32*)gbf)[i] = pk;
    }
}

// ---------------- head GEMM: C = relu(A @ W.T + b), N=128, K param ------------
__global__ __launch_bounds__(256) void gemm_head(const u16* __restrict__ A,
        const u16* __restrict__ W, const float* __restrict__ bias,
        u16* __restrict__ C, int M, int K)
{
    __shared__ u16 As[128*64];
    __shared__ u16 Bs[128*64];
    const int tid  = threadIdx.x;
    const int wid  = tid >> 6;
    const int lane = tid & 63;
    const int wr = wid >> 1, wc = wid & 1;
    const int m0 = blockIdx.x * 128;
    f32x4 acc[4][4] = {};
    for (int k0 = 0; k0 < K; k0 += 64) {
        #pragma unroll
        for (int i = 0; i < 4; ++i) {
            int L = tid + i*256;
            int rowi = L >> 3, ch = L & 7;
            int sw = ch ^ (rowi & 7);
            int gr = m0 + rowi; gr = gr < M ? gr : M-1;
            uint4 va = *reinterpret_cast<const uint4*>(&A[(size_t)gr*K + k0 + ch*8]);
            *reinterpret_cast<uint4*>(&As[(rowi*8 + sw)*8]) = va;
            uint4 vb = *reinterpret_cast<const uint4*>(&W[(size_t)rowi*K + k0 + ch*8]);
            *reinterpret_cast<uint4*>(&Bs[(rowi*8 + sw)*8]) = vb;
        }
        __syncthreads();
        const int c = lane >> 4;
        const int rl = lane & 15;
        #pragma unroll
        for (int kt = 0; kt < 2; ++kt) {
            bf16x8 af[4], bfr[4];
            #pragma unroll
            for (int f = 0; f < 4; ++f) {
                int ra = wr*64 + f*16 + rl;
                int cha = (kt*4 + c) ^ (ra & 7);
                af[f] = *reinterpret_cast<const bf16x8*>(&As[(ra*8 + cha)*8]);
                int rb = wc*64 + f*16 + rl;
                int chb = (kt*4 + c) ^ (rb & 7);
                bfr[f] = *reinterpret_cast<const bf16x8*>(&Bs[(rb*8 + chb)*8]);
            }
            #pragma unroll
            for (int fm = 0; fm < 4; ++fm)
                #pragma unroll
                for (int fn = 0; fn < 4; ++fn)
                    acc[fm][fn] = __builtin_amdgcn_mfma_f32_16x16x32_bf16(
                        af[fm], bfr[fn], acc[fm][fn], 0, 0, 0);
        }
        __syncthreads();
    }
    const int cn = lane & 15, rq = lane >> 4;
    #pragma unroll
    for (int fn = 0; fn < 4; ++fn) {
        int n = wc*64 + fn*16 + cn;
        float bb = bias[n];
        #pragma unroll
        for (int fm = 0; fm < 4; ++fm) {
            #pragma unroll
            for (int r = 0; r < 4; ++r) {
                int m = m0 + wr*64 + fm*16 + rq*4 + r;
                if (m < M) C[(size_t)m*128 + n] = f2b(fmaxf(acc[fm][fn][r] + bb, 0.f));
            }
        }
    }
}

// ---------------- head final: out[g] = dot(h2[g], p3W) + p3b ----------------
__global__ __launch_bounds__(256) void head_final(const u16* __restrict__ h2,
        const float* __restrict__ p3W, const float* __restrict__ p3b,
        float* __restrict__ out, int G)
{
    int tid = blockIdx.x*256 + threadIdx.x;
    int g = tid >> 4, sub = tid & 15;
    if (g >= G) return;
    uint4 v = *reinterpret_cast<const uint4*>(&h2[(size_t)g*128 + sub*8]);
    u32 wv[4] = {v.x, v.y, v.z, v.w};
    float s = 0.f;
    #pragma unroll
    for (int j = 0; j < 4; ++j) {
        s = fmaf(b2f((u16)(wv[j] & 0xffffu)), p3W[sub*8 + 2*j],   s);
        s = fmaf(b2f((u16)(wv[j] >> 16)),     p3W[sub*8 + 2*j+1], s);
    }
    s += __shfl_down(s, 8, 16);
    s += __shfl_down(s, 4, 16);
    s += __shfl_down(s, 2, 16);
    s += __shfl_down(s, 1, 16);
    if (sub == 0) out[g] = s + p3b[0];
}

extern "C" void kernel_launch(void* const* d_in, const int* in_sizes, int n_in,
                              void* d_out, int out_size, void* d_ws, size_t ws_size,
                              hipStream_t stream)
{
    const float* x     = (const float*)d_in[0];
    const int*   eidx  = (const int*)d_in[1];
    const float* eattr = (const float*)d_in[2];
    const int*   batch = (const int*)d_in[3];
    const float* xW    = (const float*)d_in[4];
    const float* xb    = (const float*)d_in[5];
    const float* eW    = (const float*)d_in[6];
    const float* eb    = (const float*)d_in[7];
    const float* gcnW  = (const float*)d_in[8];
    const float* gcnb  = (const float*)d_in[9];
    const float* rootE = (const float*)d_in[10];
    const float* bng   = (const float*)d_in[11];
    const float* bnb   = (const float*)d_in[12];
    const float* p1W   = (const float*)d_in[13];
    const float* p1b   = (const float*)d_in[14];
    const float* p2W   = (const float*)d_in[15];
    const float* p2b   = (const float*)d_in[16];
    const float* p3W   = (const float*)d_in[17];
    const float* p3b   = (const float*)d_in[18];
    float* out = (float*)d_out;

    const int* row = eidx;
    const int* col = eidx + NE;

    const size_t HSZ = (size_t)NN * EMB;            // 25.6M elements
    const int NWB = 5*EMB*EMB;                      // 327680

    // ---- ws layout ----
    char* p = (char*)d_ws;
    u16* t   = (u16*)p;            p += HSZ*2;      // pre-BN state
    u16* hx  = (u16*)p;            p += HSZ*2;      // GEMM output
    u16* Wb  = (u16*)p;            p += (size_t)NWB*2;
    float* eWt = (float*)p;        p += 2560*4;
    char* zbase = p;                                 // prologue-zeroed region
    int* rcnt   = (int*)p;         p += (size_t)NN*4;
    int* ccnt   = (int*)p;         p += (size_t)NN*4;
    int* fill   = (int*)p;         p += (size_t)NN*4;
    float* stats= (float*)p;       p += (size_t)NLAYERS*512*4;
    float* psum = (float*)p;       p += (size_t)NG*EMB*4;
    float* pcnt = (float*)p;       p += (size_t)NG*4;
    size_t zbytes = (size_t)(p - zbase);
    float* dinv = (float*)p;       p += (size_t)NN*4;
    float* invdg= (float*)p;       p += (size_t)NN*4;
    int* coff   = (int*)p;         p += (size_t)(NN+1)*4;
    int* bsum   = (int*)p;         p += 512*4;
    int* bbase  = (int*)p;         p += 512*4;
    int2* epack = (int2*)p;        p += (size_t)NE*8;
    u16* eab    = (u16*)p;         p += (size_t)NE*16*2;
    u16* gbf    = (u16*)p;         p += (size_t)NG*EMB*2;
    u16* h1b    = (u16*)p;         p += (size_t)NG*128*2;
    u16* h2b    = (u16*)p;         p += (size_t)NG*128*2;
    u16* Wh1    = (u16*)p;         p += (size_t)128*256*2;
    u16* Wh2    = (u16*)p;         p += (size_t)128*128*2;
    size_t NEED = (size_t)(p - (char*)d_ws);
    if (ws_size < NEED) return;    // fail absmax cleanly instead of faulting

    hipMemsetAsync(zbase, 0, zbytes, stream);

    const int NBS = (NN + 255)/256;

    embed_x<<<NN/XNB, 256, 0, stream>>>(x, xW, xb, t);
    wconv<<<(NWB+255)/256, 256, 0, stream>>>(gcnW, Wb, NWB);
    wconv<<<(128*256+255)/256, 256, 0, stream>>>(p1W, Wh1, 128*256);
    wconv<<<(128*128+255)/256, 256, 0, stream>>>(p2W, Wh2, 128*128);
    ewt_kernel<<<10, 256, 0, stream>>>(eW, eWt);
    hist_kernel<<<(NE+255)/256, 256, 0, stream>>>(row, col, rcnt, ccnt, NE);
    deg_fin<<<NBS, 256, 0, stream>>>(rcnt, dinv, invdg, NN);
    scan1<<<NBS, 256, 0, stream>>>(ccnt, bsum, NN);
    scan2<<<1, 512, 0, stream>>>(bsum, bbase, coff, NBS);
    scan3<<<NBS, 256, 0, stream>>>(ccnt, bbase, coff, NN);
    csr_fill<<<(NE+255)/256, 256, 0, stream>>>(row, col, eattr, coff, dinv, fill,
                                               epack, eab, NE);

    for (int l = 0; l < NLAYERS; ++l) {
        const u16*   Wl = Wb + (size_t)l*EMB*EMB;
        const float* bl = gcnb + (size_t)l*EMB;
        const float* rl = rootE + (size_t)l*EMB;
        const float* stPrev = stats + (size_t)(l > 0 ? l-1 : 0)*512;
        const float* gmPrev = bng + (size_t)(l > 0 ? l-1 : 0)*EMB;
        const float* btPrev = bnb + (size_t)(l > 0 ? l-1 : 0)*EMB;
        int doBN = (l > 0) ? 1 : 0;
        gemm_mfma<<<(NN+63)/64, 256, 0, stream>>>(t, Wl, bl, stPrev, gmPrev,
                                                  btPrev, doBN, hx, NN);
        gather_combine_w<<<1536, 256, 0, stream>>>(epack, eab, coff, eWt, eb,
                hx, rl, invdg, stPrev, gmPrev, btPrev, doBN, t, stats + l*512, NN);
    }

    pool_kernel<<<(NN+127)/128, 256, 0, stream>>>(t, batch,
            stats + (size_t)(NLAYERS-1)*512,
            bng + (size_t)(NLAYERS-1)*EMB, bnb + (size_t)(NLAYERS-1)*EMB,
            psum, pcnt, NN);
    pool2g<<<(NG*128+255)/256, 256, 0, stream>>>(psum, pcnt, gbf);
    gemm_head<<<NG/128, 256, 0, stream>>>(gbf, Wh1, p1b, h1b, NG, 256);
    gemm_head<<<NG/128, 256, 0, stream>>>(h1b, Wh2, p2b, h2b, NG, 128);
    head_final<<<(NG*16+255)/256, 256, 0, stream>>>(h2b, p3W, p3b, out, NG);
}